// Round 2
// baseline (293.587 us; speedup 1.0000x reference)
//
#include <hip/hip_runtime.h>

#define Bb 4
#define Nn 4096
#define Ee 2048
#define Dd 128
#define NL 11
#define NTMAX 560
#define ZS 4                     // n-splits in k_einsum
#define NCHUNK ((Nn / ZS) / 128) // 128-n chunks per block

typedef unsigned short u16;
typedef unsigned int u32;
typedef __attribute__((ext_vector_type(8))) short short8;
typedef __attribute__((ext_vector_type(4))) float floatx4;

// HW packed f32->bf16 convert (RNE), 1 VALU op vs ~10 for the manual pack.
__device__ __forceinline__ u32 pk2(float lo, float hi) {
    u32 r;
    asm("v_cvt_pk_bf16_f32 %0, %1, %2" : "=v"(r) : "v"(lo), "v"(hi));
    return r;
}
union S8U { u32 u[4]; short8 s; };

// ---- kernel 1: transpose x -> xt (bf16 pairs, d-major) + column sums ------
__global__ __launch_bounds__(256) void k_trx(const float* __restrict__ x,
                                             u32* __restrict__ xt,
                                             float* __restrict__ sums) {
    int b = blockIdx.x, n0 = blockIdx.y * 32, d0 = blockIdx.z * 32;
    int t = threadIdx.x;
    __shared__ float tile[32][33];
    int r = t >> 5, c = t & 31;
#pragma unroll
    for (int i = 0; i < 4; i++)
        tile[r + 8 * i][c] = x[((size_t)b * Nn + n0 + r + 8 * i) * Dd + d0 + c];
    __syncthreads();
#pragma unroll
    for (int i = 0; i < 2; i++) {
        int idx2 = t + 256 * i;
        int dl = idx2 >> 4, cp = idx2 & 15;
        u32 v = pk2(tile[2 * cp][dl], tile[2 * cp + 1][dl]);
        xt[(size_t)(b * Dd + d0 + dl) * (Nn / 2) + (n0 >> 1) + cp] = v;
    }
    if (t < 32) {
        float s = 0.f;
#pragma unroll
        for (int rr = 0; rr < 32; rr++) s += tile[rr][t];
        atomicAdd(&sums[b * Dd + d0 + t], s);
    }
}

// ---- kernel 2: xe0b[b][l][o] = (x0/N).W0[l] + b_table[l] ------------------
__global__ __launch_bounds__(128) void k_xe0(const float* __restrict__ sums,
                                             const float* __restrict__ wt,
                                             const float* __restrict__ bt,
                                             float* __restrict__ xe0b) {
    int b = blockIdx.x, l = blockIdx.y, o = threadIdx.x;
    const float* w0 = wt + (size_t)l * Dd * Dd + o;
    float acc = 0.f;
    for (int d = 0; d < Dd; ++d) acc += sums[b * Dd + d] * w0[(size_t)d * Dd];
    xe0b[(b * NL + l) * Dd + o] = acc * (1.0f / Nn) + bt[l * Dd + o];
}

// ---- kernel 3: wt1T[l][o][d] = bf16(W1[l][d][o])  (B-frag-ready) ----------
__global__ __launch_bounds__(256) void k_trw(const float* __restrict__ wt,
                                             u32* __restrict__ wt1T) {
    int l = blockIdx.x, d0 = blockIdx.y * 32, o0 = blockIdx.z * 32;
    int t = threadIdx.x;
    __shared__ float tile[32][33];
    const float* w1 = wt + (size_t)(NL + l) * Dd * Dd;
    int r = t >> 5, c = t & 31;
#pragma unroll
    for (int i = 0; i < 4; i++)
        tile[r + 8 * i][c] = w1[(size_t)(d0 + r + 8 * i) * Dd + o0 + c];
    __syncthreads();
#pragma unroll
    for (int i = 0; i < 2; i++) {
        int idx2 = t + 256 * i;
        int ol = idx2 >> 4, dp = idx2 & 15;
        u32 v = pk2(tile[2 * dp][ol], tile[2 * dp + 1][ol]);
        wt1T[(size_t)(l * Dd + o0 + ol) * (Dd / 2) + (d0 >> 1) + dp] = v;
    }
}

// ---- fused bucketing: count + prefix + scatter in ONE block ---------------
__global__ __launch_bounds__(1024) void k_bucket(const int* __restrict__ ord,
                                                 int* __restrict__ cnt,
                                                 int* __restrict__ offs,
                                                 int* __restrict__ idx,
                                                 int* __restrict__ tilemap) {
    __shared__ int scnt[Bb * NL], soff[Bb * NL], scur[Bb * NL];
    int t = threadIdx.x;
    if (t < Bb * NL) { scnt[t] = 0; scur[t] = 0; }
    __syncthreads();
    for (int g = t; g < Bb * Ee; g += 1024)
        atomicAdd(&scnt[(g >> 11) * NL + ord[g]], 1);
    __syncthreads();
    if (t == 0) {
        int off = 0, pos = 0;
        for (int i = 0; i < Bb * NL; i++) {
            soff[i] = off;
            offs[i] = off;
            cnt[i] = scnt[i];
            int al = (scnt[i] + 15) & ~15;
            off += al;
            for (int j = 0; j < (al >> 4); j++) tilemap[pos++] = (i << 16) | j;
        }
        for (; pos < NTMAX; pos++) tilemap[pos] = -1;
    }
    for (int i = t; i < 8960; i += 1024) idx[i] = 0;   // zero padding slots
    __syncthreads();
    for (int g = t; g < Bb * Ee; g += 1024) {
        int bk = (g >> 11) * NL + ord[g];
        int pos = soff[bk] + atomicAdd(&scur[bk], 1);
        idx[pos] = g & 2047;
    }
}

// ---- kernel 4: V2E einsum partials (ZS-way n-split), atomic fp32 accum ----
// grid (Bb, Ee/32, ZS), 256 thr. 32 edges x 128 d x (Nn/ZS) n per block.
__global__ __launch_bounds__(256) void k_einsum(const float* __restrict__ inc,
                                                const u32* __restrict__ xt,
                                                float* __restrict__ x1p) {
    int b = blockIdx.x, et0 = blockIdx.y * 32, s = blockIdx.z, t = threadIdx.x;
    int nbase = s * (Nn / ZS);
    __shared__ u32 bufA[2][32][68];
    const float* src = inc + ((size_t)b * Nn + nbase) * Ee + et0;
    int pr0 = t >> 3, c4 = t & 7;        // task rows 2*pr0, 2*pr0+1 (+64 for task1)
    int pr1 = pr0 + 32;

    int w = t >> 6, lane = t & 63, lm = lane & 15, quad = lane >> 4;
    const u32* bp0 = xt + ((size_t)b * Dd + w * 32 + lm) * (Nn / 2) + (nbase >> 1);
    const u32* bp1 = bp0 + (size_t)16 * (Nn / 2);
    floatx4 a00 = {0.f,0.f,0.f,0.f}, a01 = {0.f,0.f,0.f,0.f};
    floatx4 a10 = {0.f,0.f,0.f,0.f}, a11 = {0.f,0.f,0.f,0.f};

    float4 sA[4], sB[4];
    auto ldchunk = [&](int ci, float4* st) {
        const float* p0 = src + (size_t)(ci * 128 + 2 * pr0) * Ee + 4 * c4;
        st[0] = *(const float4*)p0;
        st[1] = *(const float4*)(p0 + Ee);
        const float* p1 = src + (size_t)(ci * 128 + 2 * pr1) * Ee + 4 * c4;
        st[2] = *(const float4*)p1;
        st[3] = *(const float4*)(p1 + Ee);
    };
    auto wrchunk = [&](int cb, const float4* st) {
        bufA[cb][4 * c4 + 0][pr0] = pk2(st[0].x, st[1].x);
        bufA[cb][4 * c4 + 1][pr0] = pk2(st[0].y, st[1].y);
        bufA[cb][4 * c4 + 2][pr0] = pk2(st[0].z, st[1].z);
        bufA[cb][4 * c4 + 3][pr0] = pk2(st[0].w, st[1].w);
        bufA[cb][4 * c4 + 0][pr1] = pk2(st[2].x, st[3].x);
        bufA[cb][4 * c4 + 1][pr1] = pk2(st[2].y, st[3].y);
        bufA[cb][4 * c4 + 2][pr1] = pk2(st[2].z, st[3].z);
        bufA[cb][4 * c4 + 3][pr1] = pk2(st[2].w, st[3].w);
    };
    ldchunk(0, sA);
    ldchunk(1, sB);
    wrchunk(0, sA);
    __syncthreads();

    for (int i = 0; i < NCHUNK; i++) {
        int cb = i & 1;
        // guarded prefetch: no redundant tail reloads (saves 32 MB HBM total)
        if (i + 2 < NCHUNK) { if (cb == 0) ldchunk(i + 2, sA); else ldchunk(i + 2, sB); }
        int ko = i * 64;
#pragma unroll
        for (int ks = 0; ks < 4; ks++) {
            short8 A0 = *(const short8*)&bufA[cb][lm][ks * 16 + quad * 4];
            short8 A1 = *(const short8*)&bufA[cb][16 + lm][ks * 16 + quad * 4];
            short8 B0 = *(const short8*)(bp0 + ko + ks * 16 + quad * 4);
            short8 B1 = *(const short8*)(bp1 + ko + ks * 16 + quad * 4);
            a00 = __builtin_amdgcn_mfma_f32_16x16x32_bf16(A0, B0, a00, 0, 0, 0);
            a01 = __builtin_amdgcn_mfma_f32_16x16x32_bf16(A0, B1, a01, 0, 0, 0);
            a10 = __builtin_amdgcn_mfma_f32_16x16x32_bf16(A1, B0, a10, 0, 0, 0);
            a11 = __builtin_amdgcn_mfma_f32_16x16x32_bf16(A1, B1, a11, 0, 0, 0);
        }
        if (i < NCHUNK - 1) { if (cb == 0) wrchunk(1, sB); else wrchunk(0, sA); }
        __syncthreads();
    }

    int db = w * 32 + lm;
    float* base = x1p + (size_t)b * Ee * Dd;
#pragma unroll
    for (int r = 0; r < 4; r++) {
        float* q0 = base + (size_t)(et0 + quad * 4 + r) * Dd;
        atomicAdd(&q0[db], a00[r]);
        atomicAdd(&q0[db + 16], a01[r]);
        float* q1 = base + (size_t)(et0 + 16 + quad * 4 + r) * Dd;
        atomicAdd(&q1[db], a10[r]);
        atomicAdd(&q1[db + 16], a11[r]);
    }
}

// ---- kernel 5: x_v via MFMA, no LDS (B-frags from wt1T, L2-hot) -----------
__global__ __launch_bounds__(256) void k_xv(const float* __restrict__ x,
                                            const u32* __restrict__ wt1T,
                                            const float* __restrict__ xe0b,
                                            float* __restrict__ outv) {
    int b = blockIdx.x, n0 = blockIdx.y * 64, t = threadIdx.x;
    int w = t >> 6, lane = t & 63, lm = lane & 15, quad = lane >> 4;
    const float* xrow = x + ((size_t)b * Nn + n0 + w * 16 + lm) * Dd;
    const u32* wrow = wt1T + (size_t)1 * Dd * (Dd / 2);   // l = 1
    floatx4 acc[8];
#pragma unroll
    for (int ot = 0; ot < 8; ot++) acc[ot] = (floatx4){0.f, 0.f, 0.f, 0.f};
#pragma unroll
    for (int ks = 0; ks < 4; ks++) {
        float4 va = *(const float4*)(xrow + ks * 32 + quad * 8);
        float4 vb = *(const float4*)(xrow + ks * 32 + quad * 8 + 4);
        S8U A;
        A.u[0] = pk2(va.x, va.y); A.u[1] = pk2(va.z, va.w);
        A.u[2] = pk2(vb.x, vb.y); A.u[3] = pk2(vb.z, vb.w);
#pragma unroll
        for (int ot = 0; ot < 8; ot++) {
            short8 Bf = *(const short8*)(wrow + (size_t)(ot * 16 + lm) * (Dd / 2) +
                                         ks * 16 + quad * 4);
            acc[ot] = __builtin_amdgcn_mfma_f32_16x16x32_bf16(A.s, Bf, acc[ot], 0, 0, 0);
        }
    }
#pragma unroll
    for (int ot = 0; ot < 8; ot++) {
        float basev = xe0b[(b * NL + 1) * Dd + ot * 16 + lm];
#pragma unroll
        for (int r = 0; r < 4; r++)
            outv[((size_t)b * Nn + n0 + w * 16 + quad * 4 + r) * Dd + ot * 16 + lm] =
                acc[ot][r] + basev;
    }
}

// ---- kernel 6: bucketed epilogue, 1 wave = one 16-edge tile, no LDS -------
__global__ __launch_bounds__(256) void k_epi(const float* __restrict__ x1p,
                                             const float* __restrict__ pref,
                                             const u32* __restrict__ wt1T,
                                             const float* __restrict__ xe0b,
                                             const int* __restrict__ cnt,
                                             const int* __restrict__ offs,
                                             const int* __restrict__ idx,
                                             const int* __restrict__ tilemap,
                                             float* __restrict__ oute) {
    int t = threadIdx.x, w = t >> 6, lane = t & 63, lm = lane & 15, quad = lane >> 4;
    int ent = tilemap[blockIdx.x * 4 + w];
    if (ent < 0) return;
    int bk = ent >> 16, j = ent & 0xffff;
    int bb = bk / NL, l = bk % NL;
    int off = offs[bk], cntv = cnt[bk];
    int eA = idx[off + j * 16 + lm];
    float rp = 1.0f / pref[bb * Ee + eA];
    const float* p0 = x1p + ((size_t)bb * Ee + eA) * Dd;
    const u32* wrow = wt1T + (size_t)l * Dd * (Dd / 2);
    floatx4 acc[8];
#pragma unroll
    for (int ot = 0; ot < 8; ot++) acc[ot] = (floatx4){0.f, 0.f, 0.f, 0.f};
#pragma unroll
    for (int ks = 0; ks < 4; ks++) {
        int d0 = ks * 32 + quad * 8;
        float4 u0 = *(const float4*)(p0 + d0);
        float4 u1 = *(const float4*)(p0 + d0 + 4);
        S8U A;
        A.u[0] = pk2(u0.x * rp, u0.y * rp);
        A.u[1] = pk2(u0.z * rp, u0.w * rp);
        A.u[2] = pk2(u1.x * rp, u1.y * rp);
        A.u[3] = pk2(u1.z * rp, u1.w * rp);
#pragma unroll
        for (int ot = 0; ot < 8; ot++) {
            short8 Bf = *(const short8*)(wrow + (size_t)(ot * 16 + lm) * (Dd / 2) +
                                         ks * 16 + quad * 4);
            acc[ot] = __builtin_amdgcn_mfma_f32_16x16x32_bf16(A.s, Bf, acc[ot], 0, 0, 0);
        }
    }
    int4 rid = *(const int4*)&idx[off + j * 16 + quad * 4];
    int rowbase = j * 16 + quad * 4;
#pragma unroll
    for (int ot = 0; ot < 8; ot++) {
        float basev = xe0b[(bb * NL + l) * Dd + ot * 16 + lm];
#pragma unroll
        for (int r = 0; r < 4; r++) {
            if (rowbase + r < cntv) {
                int e = ((const int*)&rid)[r];
                oute[((size_t)bb * Ee + e) * Dd + ot * 16 + lm] = acc[ot][r] + basev;
            }
        }
    }
}

extern "C" void kernel_launch(void* const* d_in, const int* in_sizes, int n_in,
                              void* d_out, int out_size, void* d_ws,
                              size_t ws_size, hipStream_t stream) {
    const float* x    = (const float*)d_in[0];
    const float* inc  = (const float*)d_in[1];
    const int*   ord  = (const int*)d_in[2];
    const float* pref = (const float*)d_in[3];
    const float* wt   = (const float*)d_in[7];
    const float* bt   = (const float*)d_in[8];

    float* outv = (float*)d_out;
    float* oute = outv + (size_t)Bb * Nn * Dd;

    float* ws      = (float*)d_ws;
    float* sums    = ws;                        // 512
    float* xe0b    = ws + 512;                  // 5632
    int*   cnt     = (int*)(ws + 6144);         // 44
    int*   offs    = (int*)(ws + 6192);         // 44
    int*   tilemap = (int*)(ws + 6288);         // 560
    u32*   xt      = (u32*)(ws + 8192);         // 1048576 u32 (4 MB)
    u32*   wt1T    = (u32*)(ws + 8192 + 1048576);          // 90112 u32
    int*   idx     = (int*)(ws + 8192 + 1048576 + 90112);  // 8960
    float* x1p     = ws + 8192 + 1048576 + 90112 + 8960;   // 1048576 f (4 MB)

    hipMemsetAsync(sums, 0, 512 * sizeof(float), stream);
    hipMemsetAsync(x1p, 0, (size_t)Bb * Ee * Dd * sizeof(float), stream);
    k_trx<<<dim3(Bb, Nn / 32, Dd / 32), 256, 0, stream>>>(x, xt, sums);
    k_xe0<<<dim3(Bb, NL), 128, 0, stream>>>(sums, wt, bt, xe0b);
    k_trw<<<dim3(NL, 4, 4), 256, 0, stream>>>(wt, wt1T);
    k_bucket<<<1, 1024, 0, stream>>>(ord, cnt, offs, idx, tilemap);
    k_einsum<<<dim3(Bb, Ee / 32, ZS), 256, 0, stream>>>(inc, xt, x1p);
    k_xv<<<dim3(Bb, Nn / 64), 256, 0, stream>>>(x, wt1T, xe0b, outv);
    k_epi<<<NTMAX / 4, 256, 0, stream>>>(x1p, pref, wt1T, xe0b, cnt, offs, idx,
                                         tilemap, oute);
}

// Round 4
// 290.721 us; speedup vs baseline: 1.0099x; 1.0099x over previous
//
#include <hip/hip_runtime.h>

#define Bb 4
#define Nn 4096
#define Ee 2048
#define Dd 128
#define NL 11
#define NTMAX 560
#define ZS 4                     // n-splits in k_einsum
#define CH 256                   // n per chunk (k_einsum)
#define NP (CH / 2)              // bf16 n-pairs per chunk = 128
#define LDP 132                  // LDS pair-stride: 132 % 32 == 4 -> 2-way (free)
#define NCHUNK ((Nn / ZS) / CH)  // 4 chunks per block

typedef unsigned short u16;
typedef unsigned int u32;
typedef __attribute__((ext_vector_type(8))) short short8;
typedef __attribute__((ext_vector_type(4))) float floatx4;

// HW packed f32->bf16 convert (RNE), 1 VALU op vs ~10 for the manual pack.
__device__ __forceinline__ u32 pk2(float lo, float hi) {
    u32 r;
    asm("v_cvt_pk_bf16_f32 %0, %1, %2" : "=v"(r) : "v"(lo), "v"(hi));
    return r;
}
union S8U { u32 u[4]; short8 s; };

// ---- kernel 1: transpose x -> xt (bf16 pairs, d-major) + column sums ------
__global__ __launch_bounds__(256) void k_trx(const float* __restrict__ x,
                                             u32* __restrict__ xt,
                                             float* __restrict__ sums) {
    int b = blockIdx.x, n0 = blockIdx.y * 32, d0 = blockIdx.z * 32;
    int t = threadIdx.x;
    __shared__ float tile[32][33];
    int r = t >> 5, c = t & 31;
#pragma unroll
    for (int i = 0; i < 4; i++)
        tile[r + 8 * i][c] = x[((size_t)b * Nn + n0 + r + 8 * i) * Dd + d0 + c];
    __syncthreads();
#pragma unroll
    for (int i = 0; i < 2; i++) {
        int idx2 = t + 256 * i;
        int dl = idx2 >> 4, cp = idx2 & 15;
        u32 v = pk2(tile[2 * cp][dl], tile[2 * cp + 1][dl]);
        xt[(size_t)(b * Dd + d0 + dl) * (Nn / 2) + (n0 >> 1) + cp] = v;
    }
    if (t < 32) {
        float s = 0.f;
#pragma unroll
        for (int rr = 0; rr < 32; rr++) s += tile[rr][t];
        atomicAdd(&sums[b * Dd + d0 + t], s);
    }
}

// ---- kernel 2: xe0b[b][l][o] = (x0/N).W0[l] + b_table[l] ------------------
__global__ __launch_bounds__(128) void k_xe0(const float* __restrict__ sums,
                                             const float* __restrict__ wt,
                                             const float* __restrict__ bt,
                                             float* __restrict__ xe0b) {
    int b = blockIdx.x, l = blockIdx.y, o = threadIdx.x;
    const float* w0 = wt + (size_t)l * Dd * Dd + o;
    float acc = 0.f;
    for (int d = 0; d < Dd; ++d) acc += sums[b * Dd + d] * w0[(size_t)d * Dd];
    xe0b[(b * NL + l) * Dd + o] = acc * (1.0f / Nn) + bt[l * Dd + o];
}

// ---- kernel 3: wt1T[l][o][d] = bf16(W1[l][d][o])  (B-frag-ready) ----------
__global__ __launch_bounds__(256) void k_trw(const float* __restrict__ wt,
                                             u32* __restrict__ wt1T) {
    int l = blockIdx.x, d0 = blockIdx.y * 32, o0 = blockIdx.z * 32;
    int t = threadIdx.x;
    __shared__ float tile[32][33];
    const float* w1 = wt + (size_t)(NL + l) * Dd * Dd;
    int r = t >> 5, c = t & 31;
#pragma unroll
    for (int i = 0; i < 4; i++)
        tile[r + 8 * i][c] = w1[(size_t)(d0 + r + 8 * i) * Dd + o0 + c];
    __syncthreads();
#pragma unroll
    for (int i = 0; i < 2; i++) {
        int idx2 = t + 256 * i;
        int ol = idx2 >> 4, dp = idx2 & 15;
        u32 v = pk2(tile[2 * dp][ol], tile[2 * dp + 1][ol]);
        wt1T[(size_t)(l * Dd + o0 + ol) * (Dd / 2) + (d0 >> 1) + dp] = v;
    }
}

// ---- fused bucketing: count + prefix + scatter in ONE block ---------------
__global__ __launch_bounds__(1024) void k_bucket(const int* __restrict__ ord,
                                                 int* __restrict__ cnt,
                                                 int* __restrict__ offs,
                                                 int* __restrict__ idx,
                                                 int* __restrict__ tilemap) {
    __shared__ int scnt[Bb * NL], soff[Bb * NL], scur[Bb * NL];
    int t = threadIdx.x;
    if (t < Bb * NL) { scnt[t] = 0; scur[t] = 0; }
    __syncthreads();
    for (int g = t; g < Bb * Ee; g += 1024)
        atomicAdd(&scnt[(g >> 11) * NL + ord[g]], 1);
    __syncthreads();
    if (t == 0) {
        int off = 0, pos = 0;
        for (int i = 0; i < Bb * NL; i++) {
            soff[i] = off;
            offs[i] = off;
            cnt[i] = scnt[i];
            int al = (scnt[i] + 15) & ~15;
            off += al;
            for (int j = 0; j < (al >> 4); j++) tilemap[pos++] = (i << 16) | j;
        }
        for (; pos < NTMAX; pos++) tilemap[pos] = -1;
    }
    for (int i = t; i < 8960; i += 1024) idx[i] = 0;   // zero padding slots
    __syncthreads();
    for (int g = t; g < Bb * Ee; g += 1024) {
        int bk = (g >> 11) * NL + ord[g];
        int pos = soff[bk] + atomicAdd(&scur[bk], 1);
        idx[pos] = g & 2047;
    }
}

// ---- kernel 4: V2E einsum partials (ZS-way n-split), atomic fp32 accum ----
// grid (Bb, Ee/32, ZS), 256 thr. 32 edges x 128 d x (Nn/ZS) n per block.
// 256-n chunks: 4 barriers/block, 32 MFMA/wave/barrier, 8 float4 in flight.
__global__ __launch_bounds__(256, 4) void k_einsum(const float* __restrict__ inc,
                                                   const u32* __restrict__ xt,
                                                   float* __restrict__ x1p) {
    int b = blockIdx.x, et0 = blockIdx.y * 32, s = blockIdx.z, t = threadIdx.x;
    int nbase = s * (Nn / ZS);
    __shared__ u32 bufA[2][32][LDP];
    const float* src = inc + ((size_t)b * Nn + nbase) * Ee + et0;
    int pr = t >> 3, c4 = t & 7;   // pair-rows pr+32j, edge cols 4*c4..4*c4+3

    int w = t >> 6, lane = t & 63, lm = lane & 15, quad = lane >> 4;
    const u32* bp0 = xt + ((size_t)b * Dd + w * 32 + lm) * (Nn / 2) + (nbase >> 1);
    const u32* bp1 = bp0 + (size_t)16 * (Nn / 2);
    floatx4 a00 = {0.f,0.f,0.f,0.f}, a01 = {0.f,0.f,0.f,0.f};
    floatx4 a10 = {0.f,0.f,0.f,0.f}, a11 = {0.f,0.f,0.f,0.f};

    float4 sA[8], sB[8];
    auto ldchunk = [&](int ci, float4* st) {
#pragma unroll
        for (int j = 0; j < 4; j++) {
            const float* p0 = src + (size_t)(ci * CH + 2 * (pr + 32 * j)) * Ee + 4 * c4;
            st[2 * j]     = *(const float4*)p0;
            st[2 * j + 1] = *(const float4*)(p0 + Ee);
        }
    };
    auto wrchunk = [&](int cb, const float4* st) {
#pragma unroll
        for (int j = 0; j < 4; j++) {
            bufA[cb][4 * c4 + 0][pr + 32 * j] = pk2(st[2 * j].x, st[2 * j + 1].x);
            bufA[cb][4 * c4 + 1][pr + 32 * j] = pk2(st[2 * j].y, st[2 * j + 1].y);
            bufA[cb][4 * c4 + 2][pr + 32 * j] = pk2(st[2 * j].z, st[2 * j + 1].z);
            bufA[cb][4 * c4 + 3][pr + 32 * j] = pk2(st[2 * j].w, st[2 * j + 1].w);
        }
    };
    ldchunk(0, sA);
    ldchunk(1, sB);
    wrchunk(0, sA);
    __syncthreads();

    for (int i = 0; i < NCHUNK; i++) {
        int cb = i & 1;
        // guarded prefetch: no redundant tail reloads
        if (i + 2 < NCHUNK) { if (cb == 0) ldchunk(i + 2, sA); else ldchunk(i + 2, sB); }
        int ko = i * NP;
#pragma unroll
        for (int ks = 0; ks < 8; ks++) {
            short8 A0 = *(const short8*)&bufA[cb][lm][ks * 16 + quad * 4];
            short8 A1 = *(const short8*)&bufA[cb][16 + lm][ks * 16 + quad * 4];
            short8 B0 = *(const short8*)(bp0 + ko + ks * 16 + quad * 4);
            short8 B1 = *(const short8*)(bp1 + ko + ks * 16 + quad * 4);
            a00 = __builtin_amdgcn_mfma_f32_16x16x32_bf16(A0, B0, a00, 0, 0, 0);
            a01 = __builtin_amdgcn_mfma_f32_16x16x32_bf16(A0, B1, a01, 0, 0, 0);
            a10 = __builtin_amdgcn_mfma_f32_16x16x32_bf16(A1, B0, a10, 0, 0, 0);
            a11 = __builtin_amdgcn_mfma_f32_16x16x32_bf16(A1, B1, a11, 0, 0, 0);
        }
        if (i < NCHUNK - 1) { if (cb == 0) wrchunk(1, sB); else wrchunk(0, sA); }
        __syncthreads();
    }

    int db = w * 32 + lm;
    float* base = x1p + (size_t)b * Ee * Dd;
#pragma unroll
    for (int r = 0; r < 4; r++) {
        float* q0 = base + (size_t)(et0 + quad * 4 + r) * Dd;
        atomicAdd(&q0[db], a00[r]);
        atomicAdd(&q0[db + 16], a01[r]);
        float* q1 = base + (size_t)(et0 + 16 + quad * 4 + r) * Dd;
        atomicAdd(&q1[db], a10[r]);
        atomicAdd(&q1[db + 16], a11[r]);
    }
}

// ---- kernel 5: x_v via MFMA, no LDS (B-frags from wt1T, L2-hot) -----------
__global__ __launch_bounds__(256) void k_xv(const float* __restrict__ x,
                                            const u32* __restrict__ wt1T,
                                            const float* __restrict__ xe0b,
                                            float* __restrict__ outv) {
    int b = blockIdx.x, n0 = blockIdx.y * 64, t = threadIdx.x;
    int w = t >> 6, lane = t & 63, lm = lane & 15, quad = lane >> 4;
    const float* xrow = x + ((size_t)b * Nn + n0 + w * 16 + lm) * Dd;
    const u32* wrow = wt1T + (size_t)1 * Dd * (Dd / 2);   // l = 1
    floatx4 acc[8];
#pragma unroll
    for (int ot = 0; ot < 8; ot++) acc[ot] = (floatx4){0.f, 0.f, 0.f, 0.f};
#pragma unroll
    for (int ks = 0; ks < 4; ks++) {
        float4 va = *(const float4*)(xrow + ks * 32 + quad * 8);
        float4 vb = *(const float4*)(xrow + ks * 32 + quad * 8 + 4);
        S8U A;
        A.u[0] = pk2(va.x, va.y); A.u[1] = pk2(va.z, va.w);
        A.u[2] = pk2(vb.x, vb.y); A.u[3] = pk2(vb.z, vb.w);
#pragma unroll
        for (int ot = 0; ot < 8; ot++) {
            short8 Bf = *(const short8*)(wrow + (size_t)(ot * 16 + lm) * (Dd / 2) +
                                         ks * 16 + quad * 4);
            acc[ot] = __builtin_amdgcn_mfma_f32_16x16x32_bf16(A.s, Bf, acc[ot], 0, 0, 0);
        }
    }
#pragma unroll
    for (int ot = 0; ot < 8; ot++) {
        float basev = xe0b[(b * NL + 1) * Dd + ot * 16 + lm];
#pragma unroll
        for (int r = 0; r < 4; r++)
            outv[((size_t)b * Nn + n0 + w * 16 + quad * 4 + r) * Dd + ot * 16 + lm] =
                acc[ot][r] + basev;
    }
}

// ---- kernel 6: bucketed epilogue, 1 wave = one 16-edge tile, no LDS -------
__global__ __launch_bounds__(256) void k_epi(const float* __restrict__ x1p,
                                             const float* __restrict__ pref,
                                             const u32* __restrict__ wt1T,
                                             const float* __restrict__ xe0b,
                                             const int* __restrict__ cnt,
                                             const int* __restrict__ offs,
                                             const int* __restrict__ idx,
                                             const int* __restrict__ tilemap,
                                             float* __restrict__ oute) {
    int t = threadIdx.x, w = t >> 6, lane = t & 63, lm = lane & 15, quad = lane >> 4;
    int ent = tilemap[blockIdx.x * 4 + w];
    if (ent < 0) return;
    int bk = ent >> 16, j = ent & 0xffff;
    int bb = bk / NL, l = bk % NL;
    int off = offs[bk], cntv = cnt[bk];
    int eA = idx[off + j * 16 + lm];
    float rp = 1.0f / pref[bb * Ee + eA];
    const float* p0 = x1p + ((size_t)bb * Ee + eA) * Dd;
    const u32* wrow = wt1T + (size_t)l * Dd * (Dd / 2);
    floatx4 acc[8];
#pragma unroll
    for (int ot = 0; ot < 8; ot++) acc[ot] = (floatx4){0.f, 0.f, 0.f, 0.f};
#pragma unroll
    for (int ks = 0; ks < 4; ks++) {
        int d0 = ks * 32 + quad * 8;
        float4 u0 = *(const float4*)(p0 + d0);
        float4 u1 = *(const float4*)(p0 + d0 + 4);
        S8U A;
        A.u[0] = pk2(u0.x * rp, u0.y * rp);
        A.u[1] = pk2(u0.z * rp, u0.w * rp);
        A.u[2] = pk2(u1.x * rp, u1.y * rp);
        A.u[3] = pk2(u1.z * rp, u1.w * rp);
#pragma unroll
        for (int ot = 0; ot < 8; ot++) {
            short8 Bf = *(const short8*)(wrow + (size_t)(ot * 16 + lm) * (Dd / 2) +
                                         ks * 16 + quad * 4);
            acc[ot] = __builtin_amdgcn_mfma_f32_16x16x32_bf16(A.s, Bf, acc[ot], 0, 0, 0);
        }
    }
    int4 rid = *(const int4*)&idx[off + j * 16 + quad * 4];
    int rowbase = j * 16 + quad * 4;
#pragma unroll
    for (int ot = 0; ot < 8; ot++) {
        float basev = xe0b[(bb * NL + l) * Dd + ot * 16 + lm];
#pragma unroll
        for (int r = 0; r < 4; r++) {
            if (rowbase + r < cntv) {
                int e = ((const int*)&rid)[r];
                oute[((size_t)bb * Ee + e) * Dd + ot * 16 + lm] = acc[ot][r] + basev;
            }
        }
    }
}

extern "C" void kernel_launch(void* const* d_in, const int* in_sizes, int n_in,
                              void* d_out, int out_size, void* d_ws,
                              size_t ws_size, hipStream_t stream) {
    const float* x    = (const float*)d_in[0];
    const float* inc  = (const float*)d_in[1];
    const int*   ord  = (const int*)d_in[2];
    const float* pref = (const float*)d_in[3];
    const float* wt   = (const float*)d_in[7];
    const float* bt   = (const float*)d_in[8];

    float* outv = (float*)d_out;
    float* oute = outv + (size_t)Bb * Nn * Dd;

    float* ws      = (float*)d_ws;
    float* sums    = ws;                        // 512
    float* xe0b    = ws + 512;                  // 5632
    int*   cnt     = (int*)(ws + 6144);         // 44
    int*   offs    = (int*)(ws + 6192);         // 44
    int*   tilemap = (int*)(ws + 6288);         // 560
    u32*   xt      = (u32*)(ws + 8192);         // 1048576 u32 (4 MB)
    u32*   wt1T    = (u32*)(ws + 8192 + 1048576);          // 90112 u32
    int*   idx     = (int*)(ws + 8192 + 1048576 + 90112);  // 8960
    float* x1p     = ws + 8192 + 1048576 + 90112 + 8960;   // 1048576 f (4 MB)

    hipMemsetAsync(sums, 0, 512 * sizeof(float), stream);
    hipMemsetAsync(x1p, 0, (size_t)Bb * Ee * Dd * sizeof(float), stream);
    k_trx<<<dim3(Bb, Nn / 32, Dd / 32), 256, 0, stream>>>(x, xt, sums);
    k_xe0<<<dim3(Bb, NL), 128, 0, stream>>>(sums, wt, bt, xe0b);
    k_trw<<<dim3(NL, 4, 4), 256, 0, stream>>>(wt, wt1T);
    k_bucket<<<1, 1024, 0, stream>>>(ord, cnt, offs, idx, tilemap);
    k_einsum<<<dim3(Bb, Ee / 32, ZS), 256, 0, stream>>>(inc, xt, x1p);
    k_xv<<<dim3(Bb, Nn / 64), 256, 0, stream>>>(x, wt1T, xe0b, outv);
    k_epi<<<NTMAX / 4, 256, 0, stream>>>(x1p, pref, wt1T, xe0b, cnt, offs, idx,
                                         tilemap, oute);
}